// Round 1
// baseline (707.132 us; speedup 1.0000x reference)
//
#include <hip/hip_runtime.h>
#include <math.h>

// Siddon forward projection, 128^3 grid over [-1,1]^3, voxel = 1/64.
// One thread per LOR; incremental plane-crossing traversal reproducing the
// reference's sorted-alpha segment semantics exactly.

static constexpr float VOX = 0.015625f;   // 2/128, exact power of two
static constexpr float INV_VOX = 64.0f;

__global__ __launch_bounds__(256) void siddon_fp(
    const float* __restrict__ image,
    const float* __restrict__ lors,
    float* __restrict__ out, int n)
{
    int i = blockIdx.x * blockDim.x + threadIdx.x;
    if (i >= n) return;

    const float* L = lors + (long)i * 6;
    float p0x = L[0], p0y = L[1], p0z = L[2];
    float dx  = L[3] - p0x, dy = L[4] - p0y, dz = L[5] - p0z;

    const float eps = 1e-9f;
    float dsx = (fabsf(dx) < eps) ? eps : dx;
    float dsy = (fabsf(dy) < eps) ? eps : dy;
    float dsz = (fabsf(dz) < eps) ? eps : dz;

    // Entry/exit parameters (match reference: divide by d_safe, clamp to [0,1])
    float a0 = (-1.0f - p0x) / dsx, a1 = (1.0f - p0x) / dsx;
    float axmin = fminf(a0, a1), axmax = fmaxf(a0, a1);
    a0 = (-1.0f - p0y) / dsy; a1 = (1.0f - p0y) / dsy;
    float aymin = fminf(a0, a1), aymax = fmaxf(a0, a1);
    a0 = (-1.0f - p0z) / dsz; a1 = (1.0f - p0z) / dsz;
    float azmin = fminf(a0, a1), azmax = fmaxf(a0, a1);

    float amin = fmaxf(fmaxf(axmin, aymin), fmaxf(azmin, 0.0f));
    float amax = fminf(fminf(axmax, aymax), fminf(azmax, 1.0f));

    float acc = 0.0f;
    if (amax > amin) {
        float invx = 1.0f / dsx, invy = 1.0f / dsy, invz = 1.0f / dsz;

        int ipx, ipy, ipz, stx, sty, stz;
        float alx, aly, alz;

        // For each axis: find first plane index whose alpha is > amin when
        // walking in increasing-alpha order; compute its alpha exactly as the
        // reference does: (plane - p0) / d_safe with plane = i*VOX - 1 (exact).
        {
            float t = (fmaf(amin, dsx, p0x) + 1.0f) * INV_VOX;
            if (dsx > 0.0f) { ipx = (int)floorf(t) + 1; if (ipx < 0) ipx = 0; stx = 1; }
            else            { ipx = (int)ceilf(t) - 1;  if (ipx > 128) ipx = 128; stx = -1; }
            alx = ((unsigned)ipx <= 128u)
                ? (fmaf((float)ipx, VOX, -1.0f) - p0x) * invx : INFINITY;
        }
        {
            float t = (fmaf(amin, dsy, p0y) + 1.0f) * INV_VOX;
            if (dsy > 0.0f) { ipy = (int)floorf(t) + 1; if (ipy < 0) ipy = 0; sty = 1; }
            else            { ipy = (int)ceilf(t) - 1;  if (ipy > 128) ipy = 128; sty = -1; }
            aly = ((unsigned)ipy <= 128u)
                ? (fmaf((float)ipy, VOX, -1.0f) - p0y) * invy : INFINITY;
        }
        {
            float t = (fmaf(amin, dsz, p0z) + 1.0f) * INV_VOX;
            if (dsz > 0.0f) { ipz = (int)floorf(t) + 1; if (ipz < 0) ipz = 0; stz = 1; }
            else            { ipz = (int)ceilf(t) - 1;  if (ipz > 128) ipz = 128; stz = -1; }
            alz = ((unsigned)ipz <= 128u)
                ? (fmaf((float)ipz, VOX, -1.0f) - p0z) * invz : INFINITY;
        }

        float acur = amin;
        while (true) {
            float anext = amax; int which = 3;
            if (alx < anext) { anext = alx; which = 0; }
            if (aly < anext) { anext = aly; which = 1; }
            if (alz < anext) { anext = alz; which = 2; }

            float diff = anext - acur;
            if (diff > 0.0f) {
                float mid = fmaf(0.5f, diff, acur);
                float px = fmaf(mid, dx, p0x);
                float py = fmaf(mid, dy, p0y);
                float pz = fmaf(mid, dz, p0z);
                float fx = floorf((px + 1.0f) * INV_VOX);
                float fy = floorf((py + 1.0f) * INV_VOX);
                float fz = floorf((pz + 1.0f) * INV_VOX);
                if (fx >= 0.0f && fx < 128.0f &&
                    fy >= 0.0f && fy < 128.0f &&
                    fz >= 0.0f && fz < 128.0f) {
                    int idx = (((int)fx) << 14) | (((int)fy) << 7) | ((int)fz);
                    acc = fmaf(diff, image[idx], acc);
                }
            }
            acur = anext;
            if (which == 3) break;

            if (which == 0) {
                ipx += stx;
                alx = ((unsigned)ipx <= 128u)
                    ? (fmaf((float)ipx, VOX, -1.0f) - p0x) * invx : INFINITY;
            } else if (which == 1) {
                ipy += sty;
                aly = ((unsigned)ipy <= 128u)
                    ? (fmaf((float)ipy, VOX, -1.0f) - p0y) * invy : INFINITY;
            } else {
                ipz += stz;
                alz = ((unsigned)ipz <= 128u)
                    ? (fmaf((float)ipz, VOX, -1.0f) - p0z) * invz : INFINITY;
            }
        }
        acc *= sqrtf(dx*dx + dy*dy + dz*dz);
    }
    out[i] = acc;
}

extern "C" void kernel_launch(void* const* d_in, const int* in_sizes, int n_in,
                              void* d_out, int out_size, void* d_ws, size_t ws_size,
                              hipStream_t stream) {
    const float* image = (const float*)d_in[0];   // [128,128,128] f32
    const float* lors  = (const float*)d_in[1];   // [N,6] f32
    float* out = (float*)d_out;                   // [N] f32
    int n = out_size;
    int block = 256;
    int grid = (n + block - 1) / block;
    hipLaunchKernelGGL(siddon_fp, dim3(grid), dim3(block), 0, stream,
                       image, lors, out, n);
}

// Round 2
// 87.559 us; speedup vs baseline: 8.0761x; 8.0761x over previous
//
#include <hip/hip_runtime.h>
#include <math.h>

// Siddon forward projection, 128^3 grid over [-1,1]^3, voxel = 1/64.
// K lanes per LOR, each traversing an alpha-chunk [amin + k*s, amin+(k+1)*s];
// chunk boundaries only split segments within a voxel, preserving the sum.
// Branchless (select-based) axis advance to avoid exec-mask divergence.

static constexpr float VOX = 0.015625f;   // 2/128, exact power of two
static constexpr float INV_VOX = 64.0f;
static constexpr int   K = 8;             // lanes (chunks) per ray
static constexpr int   LOGK = 3;

__global__ __launch_bounds__(256) void siddon_fp(
    const float* __restrict__ image,
    const float* __restrict__ lors,
    float* __restrict__ out, int n)
{
    int t   = blockIdx.x * blockDim.x + threadIdx.x;
    int ray = t >> LOGK;
    int k   = t & (K - 1);
    if (ray >= n) return;

    const float* L = lors + (long)ray * 6;
    float p0x = L[0], p0y = L[1], p0z = L[2];
    float dx  = L[3] - p0x, dy = L[4] - p0y, dz = L[5] - p0z;

    const float eps = 1e-9f;
    float dsx = (fabsf(dx) < eps) ? eps : dx;
    float dsy = (fabsf(dy) < eps) ? eps : dy;
    float dsz = (fabsf(dz) < eps) ? eps : dz;

    // Entry/exit parameters (match reference: divide by d_safe, clamp [0,1])
    float a0 = (-1.0f - p0x) / dsx, a1 = (1.0f - p0x) / dsx;
    float axmin = fminf(a0, a1), axmax = fmaxf(a0, a1);
    a0 = (-1.0f - p0y) / dsy; a1 = (1.0f - p0y) / dsy;
    float aymin = fminf(a0, a1), aymax = fmaxf(a0, a1);
    a0 = (-1.0f - p0z) / dsz; a1 = (1.0f - p0z) / dsz;
    float azmin = fminf(a0, a1), azmax = fmaxf(a0, a1);

    float amin = fmaxf(fmaxf(axmin, aymin), fmaxf(azmin, 0.0f));
    float amax = fminf(fminf(axmax, aymax), fminf(azmax, 1.0f));

    float acc = 0.0f;
    if (amax > amin) {
        // This lane's alpha sub-range. fmaf(k, s, amin) is computed with the
        // identical expression in adjacent lanes -> chunk endpoints match
        // bit-exactly (no gaps / overlaps).
        float s      = (amax - amin) * (1.0f / (float)K);
        float astart = fmaf((float)k,       s, amin);
        float aend   = (k == K - 1) ? amax : fmaf((float)(k + 1), s, amin);

        if (aend > astart) {
            float invx = 1.0f / dsx, invy = 1.0f / dsy, invz = 1.0f / dsz;

            int ipx, ipy, ipz, stx, sty, stz;
            float alx, aly, alz;

            // Per axis: first plane index whose alpha is > astart in walk
            // order; alpha computed exactly as the reference does:
            // (plane - p0) * (1/d_safe), plane = i*VOX - 1 (exact fp).
            {
                float tt = (fmaf(astart, dsx, p0x) + 1.0f) * INV_VOX;
                if (dsx > 0.0f) { ipx = (int)floorf(tt) + 1; if (ipx < 0) ipx = 0; stx = 1; }
                else            { ipx = (int)ceilf(tt) - 1;  if (ipx > 128) ipx = 128; stx = -1; }
                alx = ((unsigned)ipx <= 128u)
                    ? (fmaf((float)ipx, VOX, -1.0f) - p0x) * invx : INFINITY;
            }
            {
                float tt = (fmaf(astart, dsy, p0y) + 1.0f) * INV_VOX;
                if (dsy > 0.0f) { ipy = (int)floorf(tt) + 1; if (ipy < 0) ipy = 0; sty = 1; }
                else            { ipy = (int)ceilf(tt) - 1;  if (ipy > 128) ipy = 128; sty = -1; }
                aly = ((unsigned)ipy <= 128u)
                    ? (fmaf((float)ipy, VOX, -1.0f) - p0y) * invy : INFINITY;
            }
            {
                float tt = (fmaf(astart, dsz, p0z) + 1.0f) * INV_VOX;
                if (dsz > 0.0f) { ipz = (int)floorf(tt) + 1; if (ipz < 0) ipz = 0; stz = 1; }
                else            { ipz = (int)ceilf(tt) - 1;  if (ipz > 128) ipz = 128; stz = -1; }
                alz = ((unsigned)ipz <= 128u)
                    ? (fmaf((float)ipz, VOX, -1.0f) - p0z) * invz : INFINITY;
            }

            float acur = astart;
            while (true) {
                float anext = fminf(fminf(alx, aly), alz);
                float astop = fminf(anext, aend);
                float diff  = astop - acur;

                if (diff > 0.0f) {
                    float mid = fmaf(0.5f, diff, acur);
                    float px = fmaf(mid, dx, p0x);
                    float py = fmaf(mid, dy, p0y);
                    float pz = fmaf(mid, dz, p0z);
                    float fx = floorf((px + 1.0f) * INV_VOX);
                    float fy = floorf((py + 1.0f) * INV_VOX);
                    float fz = floorf((pz + 1.0f) * INV_VOX);
                    if (fx >= 0.0f && fx < 128.0f &&
                        fy >= 0.0f && fy < 128.0f &&
                        fz >= 0.0f && fz < 128.0f) {
                        int idx = (((int)fx) << 14) | (((int)fy) << 7) | ((int)fz);
                        acc = fmaf(diff, image[idx], acc);
                    }
                }

                if (anext >= aend) break;
                acur = anext;

                // Branchless advance: compute candidate next state for every
                // axis, select with the crossing predicate (-> v_cndmask).
                bool cx = (alx <= anext);
                bool cy = (aly <= anext);
                bool cz = (alz <= anext);

                int ipx2 = ipx + stx;
                int ipy2 = ipy + sty;
                int ipz2 = ipz + stz;
                float alx2 = ((unsigned)ipx2 <= 128u)
                    ? (fmaf((float)ipx2, VOX, -1.0f) - p0x) * invx : INFINITY;
                float aly2 = ((unsigned)ipy2 <= 128u)
                    ? (fmaf((float)ipy2, VOX, -1.0f) - p0y) * invy : INFINITY;
                float alz2 = ((unsigned)ipz2 <= 128u)
                    ? (fmaf((float)ipz2, VOX, -1.0f) - p0z) * invz : INFINITY;

                ipx = cx ? ipx2 : ipx;  alx = cx ? alx2 : alx;
                ipy = cy ? ipy2 : ipy;  aly = cy ? aly2 : aly;
                ipz = cz ? ipz2 : ipz;  alz = cz ? alz2 : alz;
            }
            acc *= sqrtf(dx*dx + dy*dy + dz*dz);
        }
    }

    // Reduce the K chunk partial sums within each K-lane group.
    acc += __shfl_xor(acc, 1);
    acc += __shfl_xor(acc, 2);
    acc += __shfl_xor(acc, 4);
    if (k == 0) out[ray] = acc;
}

extern "C" void kernel_launch(void* const* d_in, const int* in_sizes, int n_in,
                              void* d_out, int out_size, void* d_ws, size_t ws_size,
                              hipStream_t stream) {
    const float* image = (const float*)d_in[0];   // [128,128,128] f32
    const float* lors  = (const float*)d_in[1];   // [N,6] f32
    float* out = (float*)d_out;                   // [N] f32
    int n = out_size;
    long total = (long)n * K;
    int block = 256;
    int grid = (int)((total + block - 1) / block);
    hipLaunchKernelGGL(siddon_fp, dim3(grid), dim3(block), 0, stream,
                       image, lors, out, n);
}

// Round 3
// 73.879 us; speedup vs baseline: 9.5715x; 1.1852x over previous
//
#include <hip/hip_runtime.h>
#include <math.h>

// Siddon forward projection, 128^3 grid over [-1,1]^3, voxel = 1/64.
// K lanes per LOR, each traversing an alpha-chunk; traversal unrolled in
// batches of 4 so 4 scattered image loads are in flight per wave (MLP).

static constexpr float VOX = 0.015625f;   // 2/128, exact power of two
static constexpr float INV_VOX = 64.0f;
static constexpr int   K = 16;            // lanes (chunks) per ray
static constexpr int   LOGK = 4;
static constexpr int   BATCH = 4;

__global__ __launch_bounds__(256) void siddon_fp(
    const float* __restrict__ image,
    const float* __restrict__ lors,
    float* __restrict__ out, int n)
{
    int t   = blockIdx.x * blockDim.x + threadIdx.x;
    int ray = t >> LOGK;
    int k   = t & (K - 1);
    if (ray >= n) return;

    const float* L = lors + (long)ray * 6;
    float p0x = L[0], p0y = L[1], p0z = L[2];
    float dx  = L[3] - p0x, dy = L[4] - p0y, dz = L[5] - p0z;

    const float eps = 1e-9f;
    float dsx = (fabsf(dx) < eps) ? eps : dx;
    float dsy = (fabsf(dy) < eps) ? eps : dy;
    float dsz = (fabsf(dz) < eps) ? eps : dz;

    // Entry/exit parameters (match reference: divide by d_safe, clamp [0,1])
    float a0 = (-1.0f - p0x) / dsx, a1 = (1.0f - p0x) / dsx;
    float axmin = fminf(a0, a1), axmax = fmaxf(a0, a1);
    a0 = (-1.0f - p0y) / dsy; a1 = (1.0f - p0y) / dsy;
    float aymin = fminf(a0, a1), aymax = fmaxf(a0, a1);
    a0 = (-1.0f - p0z) / dsz; a1 = (1.0f - p0z) / dsz;
    float azmin = fminf(a0, a1), azmax = fmaxf(a0, a1);

    float amin = fmaxf(fmaxf(axmin, aymin), fmaxf(azmin, 0.0f));
    float amax = fminf(fminf(axmax, aymax), fminf(azmax, 1.0f));

    float acc = 0.0f;
    if (amax > amin) {
        // This lane's alpha sub-range; fmaf(k, s, amin) is evaluated with the
        // identical expression in adjacent lanes -> endpoints match bit-exact.
        float s      = (amax - amin) * (1.0f / (float)K);
        float astart = fmaf((float)k,       s, amin);
        float aend   = (k == K - 1) ? amax : fmaf((float)(k + 1), s, amin);

        if (aend > astart) {
            float invx = 1.0f / dsx, invy = 1.0f / dsy, invz = 1.0f / dsz;

            int ipx, ipy, ipz, stx, sty, stz;
            float alx, aly, alz;

            // Per axis: first plane index with alpha > astart in walk order;
            // alpha computed as (plane - p0) * (1/d_safe), plane = i*VOX - 1.
            {
                float tt = (fmaf(astart, dsx, p0x) + 1.0f) * INV_VOX;
                if (dsx > 0.0f) { ipx = (int)floorf(tt) + 1; if (ipx < 0) ipx = 0; stx = 1; }
                else            { ipx = (int)ceilf(tt) - 1;  if (ipx > 128) ipx = 128; stx = -1; }
                alx = ((unsigned)ipx <= 128u)
                    ? (fmaf((float)ipx, VOX, -1.0f) - p0x) * invx : INFINITY;
            }
            {
                float tt = (fmaf(astart, dsy, p0y) + 1.0f) * INV_VOX;
                if (dsy > 0.0f) { ipy = (int)floorf(tt) + 1; if (ipy < 0) ipy = 0; sty = 1; }
                else            { ipy = (int)ceilf(tt) - 1;  if (ipy > 128) ipy = 128; sty = -1; }
                aly = ((unsigned)ipy <= 128u)
                    ? (fmaf((float)ipy, VOX, -1.0f) - p0y) * invy : INFINITY;
            }
            {
                float tt = (fmaf(astart, dsz, p0z) + 1.0f) * INV_VOX;
                if (dsz > 0.0f) { ipz = (int)floorf(tt) + 1; if (ipz < 0) ipz = 0; stz = 1; }
                else            { ipz = (int)ceilf(tt) - 1;  if (ipz > 128) ipz = 128; stz = -1; }
                alz = ((unsigned)ipz <= 128u)
                    ? (fmaf((float)ipz, VOX, -1.0f) - p0z) * invz : INFINITY;
            }

            float acur = astart;
            bool done = false;
            while (!done) {
                float diffs[BATCH];
                int   idxs[BATCH];

                #pragma unroll
                for (int j = 0; j < BATCH; ++j) {
                    float anext = fminf(fminf(alx, aly), alz);
                    float astop = fminf(anext, aend);
                    float diff  = astop - acur;

                    float mid = fmaf(0.5f, diff, acur);
                    float px = fmaf(mid, dx, p0x);
                    float py = fmaf(mid, dy, p0y);
                    float pz = fmaf(mid, dz, p0z);
                    float fx = floorf((px + 1.0f) * INV_VOX);
                    float fy = floorf((py + 1.0f) * INV_VOX);
                    float fz = floorf((pz + 1.0f) * INV_VOX);
                    bool inb = (fx >= 0.0f) & (fx < 128.0f) &
                               (fy >= 0.0f) & (fy < 128.0f) &
                               (fz >= 0.0f) & (fz < 128.0f);
                    bool use = inb & (diff > 0.0f);
                    int idx = (((int)fx) << 14) | (((int)fy) << 7) | ((int)fz);
                    idxs[j]  = use ? idx  : 0;
                    diffs[j] = use ? diff : 0.0f;

                    acur = astop;
                    done |= (anext >= aend);

                    // Branchless advance of every crossing axis.
                    bool cx = (alx <= anext);
                    bool cy = (aly <= anext);
                    bool cz = (alz <= anext);
                    int ipx2 = ipx + stx;
                    int ipy2 = ipy + sty;
                    int ipz2 = ipz + stz;
                    float alx2 = ((unsigned)ipx2 <= 128u)
                        ? (fmaf((float)ipx2, VOX, -1.0f) - p0x) * invx : INFINITY;
                    float aly2 = ((unsigned)ipy2 <= 128u)
                        ? (fmaf((float)ipy2, VOX, -1.0f) - p0y) * invy : INFINITY;
                    float alz2 = ((unsigned)ipz2 <= 128u)
                        ? (fmaf((float)ipz2, VOX, -1.0f) - p0z) * invz : INFINITY;
                    ipx = cx ? ipx2 : ipx;  alx = cx ? alx2 : alx;
                    ipy = cy ? ipy2 : ipy;  aly = cy ? aly2 : aly;
                    ipz = cz ? ipz2 : ipz;  alz = cz ? alz2 : alz;
                }

                // 4 independent scattered loads in flight, then accumulate.
                float v0 = image[idxs[0]];
                float v1 = image[idxs[1]];
                float v2 = image[idxs[2]];
                float v3 = image[idxs[3]];
                acc = fmaf(diffs[0], v0, acc);
                acc = fmaf(diffs[1], v1, acc);
                acc = fmaf(diffs[2], v2, acc);
                acc = fmaf(diffs[3], v3, acc);
            }
            acc *= sqrtf(dx*dx + dy*dy + dz*dz);
        }
    }

    // Reduce the K chunk partial sums within each K-lane group.
    acc += __shfl_xor(acc, 1);
    acc += __shfl_xor(acc, 2);
    acc += __shfl_xor(acc, 4);
    acc += __shfl_xor(acc, 8);
    if (k == 0) out[ray] = acc;
}

extern "C" void kernel_launch(void* const* d_in, const int* in_sizes, int n_in,
                              void* d_out, int out_size, void* d_ws, size_t ws_size,
                              hipStream_t stream) {
    const float* image = (const float*)d_in[0];   // [128,128,128] f32
    const float* lors  = (const float*)d_in[1];   // [N,6] f32
    float* out = (float*)d_out;                   // [N] f32
    int n = out_size;
    long total = (long)n * K;
    int block = 256;
    int grid = (int)((total + block - 1) / block);
    hipLaunchKernelGGL(siddon_fp, dim3(grid), dim3(block), 0, stream,
                       image, lors, out, n);
}

// Round 4
// 67.287 us; speedup vs baseline: 10.5092x; 1.0980x over previous
//
#include <hip/hip_runtime.h>
#include <math.h>

// Siddon forward projection, 128^3 grid over [-1,1]^3, voxel = 1/64.
// K=16 lanes per LOR (alpha chunks). Incremental Siddon traversal:
// integer voxel indices + per-axis alpha increments, counted loop with a
// 2-stage software pipeline (two 4-load batches in flight).

static constexpr float VOX = 0.015625f;   // 2/128, exact power of two
static constexpr float INV_VOX = 64.0f;
static constexpr int   K = 16;
static constexpr int   LOGK = 4;

struct TState {
  float alx, aly, alz;   // next-crossing alpha per axis
  float dax, day, daz;   // alpha increment per crossing
  float acur, aend;
  int   ix, iy, iz;      // current voxel
  int   stx, sty, stz;   // walk direction
};

__device__ __forceinline__ void step4(TState& S, int idx4[4], float dif4[4]) {
#pragma unroll
  for (int j = 0; j < 4; ++j) {
    float anext = fminf(fminf(S.alx, S.aly), S.alz);
    float astop = fminf(anext, S.aend);
    float diff  = astop - S.acur;
    int   orv   = S.ix | S.iy | S.iz;
    bool  use   = (diff > 0.0f) && (((unsigned)orv & ~127u) == 0u);
    int   idx   = (S.ix << 14) | (S.iy << 7) | S.iz;
    idx4[j] = use ? idx : 0;
    dif4[j] = use ? diff : 0.0f;
    S.acur = astop;
    bool cx = S.alx <= anext;
    bool cy = S.aly <= anext;
    bool cz = S.alz <= anext;
    S.ix += cx ? S.stx : 0;  S.alx += cx ? S.dax : 0.0f;
    S.iy += cy ? S.sty : 0;  S.aly += cy ? S.day : 0.0f;
    S.iz += cz ? S.stz : 0;  S.alz += cz ? S.daz : 0.0f;
  }
}

// First plane index strictly past astart in walk order, its alpha, the alpha
// increment, the voxel index containing astart, and the exact number of
// crossings in (astart, aend].
__device__ __forceinline__ void axis_init(float astart, float aend, float p0,
                                          float ds, float inv,
                                          int& st, int& iv, float& al, float& da,
                                          int& cnt) {
  float ts = (fmaf(astart, ds, p0) + 1.0f) * INV_VOX;
  float te = (fmaf(aend,   ds, p0) + 1.0f) * INV_VOX;
  int ip;
  if (ds > 0.0f) {
    ip = (int)floorf(ts) + 1;
    int il = (int)floorf(te); if (il > 128) il = 128;
    cnt = il - ip + 1; st = 1; iv = ip - 1;
  } else {
    ip = (int)ceilf(ts) - 1;
    int il = (int)ceilf(te); if (il < 0) il = 0;
    cnt = ip - il + 1; st = -1; iv = ip;
  }
  if (cnt < 0) cnt = 0;
  al = (fmaf((float)ip, VOX, -1.0f) - p0) * inv;
  da = VOX * fabsf(inv);
}

__global__ __launch_bounds__(256) void siddon_fp(
    const float* __restrict__ image,
    const float* __restrict__ lors,
    float* __restrict__ out, int n)
{
  int t   = blockIdx.x * blockDim.x + threadIdx.x;
  int ray = t >> LOGK;
  int k   = t & (K - 1);
  if (ray >= n) return;

  const float* L = lors + (long)ray * 6;
  float p0x = L[0], p0y = L[1], p0z = L[2];
  float dx  = L[3] - p0x, dy = L[4] - p0y, dz = L[5] - p0z;

  const float eps = 1e-9f;
  float dsx = (fabsf(dx) < eps) ? eps : dx;
  float dsy = (fabsf(dy) < eps) ? eps : dy;
  float dsz = (fabsf(dz) < eps) ? eps : dz;

  float invx = __builtin_amdgcn_rcpf(dsx);
  float invy = __builtin_amdgcn_rcpf(dsy);
  float invz = __builtin_amdgcn_rcpf(dsz);

  float a0 = (-1.0f - p0x) * invx, a1 = (1.0f - p0x) * invx;
  float axmin = fminf(a0, a1), axmax = fmaxf(a0, a1);
  a0 = (-1.0f - p0y) * invy; a1 = (1.0f - p0y) * invy;
  float aymin = fminf(a0, a1), aymax = fmaxf(a0, a1);
  a0 = (-1.0f - p0z) * invz; a1 = (1.0f - p0z) * invz;
  float azmin = fminf(a0, a1), azmax = fmaxf(a0, a1);

  float amin = fmaxf(fmaxf(axmin, aymin), fmaxf(azmin, 0.0f));
  float amax = fminf(fminf(axmax, aymax), fminf(azmax, 1.0f));

  float acc0 = 0.0f, acc1 = 0.0f;
  if (amax > amin) {
    float s      = (amax - amin) * (1.0f / (float)K);
    float astart = fmaf((float)k, s, amin);
    float aend   = (k == K - 1) ? amax : fmaf((float)(k + 1), s, amin);

    TState S;
    S.acur = astart; S.aend = aend;
    int cx, cy, cz;
    axis_init(astart, aend, p0x, dsx, invx, S.stx, S.ix, S.alx, S.dax, cx);
    axis_init(astart, aend, p0y, dsy, invy, S.sty, S.iy, S.aly, S.day, cy);
    axis_init(astart, aend, p0z, dsz, invz, S.stz, S.iz, S.alz, S.daz, cz);

    int ns = cx + cy + cz + 3;          // +1 final partial, +2 cushion
    int nb = (ns + 3) >> 2;             // batches of 4
    int npairs = nb >> 1;               // consumed = 2*npairs + 1 >= nb

    int   idxA[4], idxB[4];
    float difA[4], difB[4];
    float vA0, vA1, vA2, vA3, vB0, vB1, vB2, vB3;

    step4(S, idxA, difA);
    vA0 = image[idxA[0]]; vA1 = image[idxA[1]];
    vA2 = image[idxA[2]]; vA3 = image[idxA[3]];

    for (int p = 0; p < npairs; ++p) {
      step4(S, idxB, difB);
      vB0 = image[idxB[0]]; vB1 = image[idxB[1]];
      vB2 = image[idxB[2]]; vB3 = image[idxB[3]];
      acc0 = fmaf(difA[0], vA0, acc0);
      acc1 = fmaf(difA[1], vA1, acc1);
      acc0 = fmaf(difA[2], vA2, acc0);
      acc1 = fmaf(difA[3], vA3, acc1);

      step4(S, idxA, difA);
      vA0 = image[idxA[0]]; vA1 = image[idxA[1]];
      vA2 = image[idxA[2]]; vA3 = image[idxA[3]];
      acc0 = fmaf(difB[0], vB0, acc0);
      acc1 = fmaf(difB[1], vB1, acc1);
      acc0 = fmaf(difB[2], vB2, acc0);
      acc1 = fmaf(difB[3], vB3, acc1);
    }
    acc0 = fmaf(difA[0], vA0, acc0);
    acc1 = fmaf(difA[1], vA1, acc1);
    acc0 = fmaf(difA[2], vA2, acc0);
    acc1 = fmaf(difA[3], vA3, acc1);

    float rlen = sqrtf(dx * dx + dy * dy + dz * dz);
    acc0 = (acc0 + acc1) * rlen;
    acc1 = 0.0f;
  }

  // Reduce the K chunk partials within each 16-lane group.
  float acc = acc0 + acc1;
  acc += __shfl_xor(acc, 1);
  acc += __shfl_xor(acc, 2);
  acc += __shfl_xor(acc, 4);
  acc += __shfl_xor(acc, 8);
  if (k == 0) out[ray] = acc;
}

extern "C" void kernel_launch(void* const* d_in, const int* in_sizes, int n_in,
                              void* d_out, int out_size, void* d_ws, size_t ws_size,
                              hipStream_t stream) {
  const float* image = (const float*)d_in[0];   // [128,128,128] f32
  const float* lors  = (const float*)d_in[1];   // [N,6] f32
  float* out = (float*)d_out;                   // [N] f32
  int n = out_size;
  long total = (long)n * K;
  int block = 256;
  int grid = (int)((total + block - 1) / block);
  hipLaunchKernelGGL(siddon_fp, dim3(grid), dim3(block), 0, stream,
                     image, lors, out, n);
}

// Round 5
// 67.276 us; speedup vs baseline: 10.5110x; 1.0002x over previous
//
#include <hip/hip_runtime.h>
#include <math.h>

// Siddon forward projection, 128^3 grid over [-1,1]^3, voxel = 1/64.
// K=16 lanes per LOR (alpha chunks). Incremental Siddon traversal with a
// depth-3 software pipeline: 3 batches of 4 scattered loads in flight.

static constexpr float VOX = 0.015625f;   // 2/128, exact power of two
static constexpr float INV_VOX = 64.0f;
static constexpr int   K = 16;
static constexpr int   LOGK = 4;

struct TState {
  float alx, aly, alz;   // next-crossing alpha per axis
  float dax, day, daz;   // alpha increment per crossing
  float acur, aend;
  int   ix, iy, iz;      // current voxel
  int   stx, sty, stz;   // walk direction
};

__device__ __forceinline__ void step4(TState& S, int idx4[4], float dif4[4]) {
#pragma unroll
  for (int j = 0; j < 4; ++j) {
    float anext = fminf(fminf(S.alx, S.aly), S.alz);
    float astop = fminf(anext, S.aend);
    float diff  = astop - S.acur;
    unsigned orv = (unsigned)(S.ix | S.iy | S.iz);
    bool  use   = (diff > 0.0f) & (orv < 128u);
    int   idx   = (S.ix << 14) | (S.iy << 7) | S.iz;
    idx4[j] = use ? idx : 0;
    dif4[j] = use ? diff : 0.0f;
    S.acur = astop;
    bool cx = S.alx <= anext;
    bool cy = S.aly <= anext;
    bool cz = S.alz <= anext;
    S.ix += cx ? S.stx : 0;  S.alx += cx ? S.dax : 0.0f;
    S.iy += cy ? S.sty : 0;  S.aly += cy ? S.day : 0.0f;
    S.iz += cz ? S.stz : 0;  S.alz += cz ? S.daz : 0.0f;
  }
}

// First plane index strictly past astart in walk order, its alpha, the alpha
// increment, the voxel containing astart, and the crossing count in
// (astart, aend].
__device__ __forceinline__ void axis_init(float astart, float aend, float p0,
                                          float ds, float inv,
                                          int& st, int& iv, float& al, float& da,
                                          int& cnt) {
  float ts = (fmaf(astart, ds, p0) + 1.0f) * INV_VOX;
  float te = (fmaf(aend,   ds, p0) + 1.0f) * INV_VOX;
  int ip;
  if (ds > 0.0f) {
    ip = (int)floorf(ts) + 1;
    int il = (int)floorf(te); if (il > 128) il = 128;
    cnt = il - ip + 1; st = 1; iv = ip - 1;
  } else {
    ip = (int)ceilf(ts) - 1;
    int il = (int)ceilf(te); if (il < 0) il = 0;
    cnt = ip - il + 1; st = -1; iv = ip;
  }
  if (cnt < 0) cnt = 0;
  al = (fmaf((float)ip, VOX, -1.0f) - p0) * inv;
  da = VOX * fabsf(inv);
}

__global__ __launch_bounds__(256) void siddon_fp(
    const float* __restrict__ image,
    const float* __restrict__ lors,
    float* __restrict__ out, int n)
{
  int t   = blockIdx.x * blockDim.x + threadIdx.x;
  int ray = t >> LOGK;
  int k   = t & (K - 1);
  if (ray >= n) return;

  const float* L = lors + (long)ray * 6;
  float p0x = L[0], p0y = L[1], p0z = L[2];
  float dx  = L[3] - p0x, dy = L[4] - p0y, dz = L[5] - p0z;

  const float eps = 1e-9f;
  float dsx = (fabsf(dx) < eps) ? eps : dx;
  float dsy = (fabsf(dy) < eps) ? eps : dy;
  float dsz = (fabsf(dz) < eps) ? eps : dz;

  float invx = __builtin_amdgcn_rcpf(dsx);
  float invy = __builtin_amdgcn_rcpf(dsy);
  float invz = __builtin_amdgcn_rcpf(dsz);

  float a0 = (-1.0f - p0x) * invx, a1 = (1.0f - p0x) * invx;
  float axmin = fminf(a0, a1), axmax = fmaxf(a0, a1);
  a0 = (-1.0f - p0y) * invy; a1 = (1.0f - p0y) * invy;
  float aymin = fminf(a0, a1), aymax = fmaxf(a0, a1);
  a0 = (-1.0f - p0z) * invz; a1 = (1.0f - p0z) * invz;
  float azmin = fminf(a0, a1), azmax = fmaxf(a0, a1);

  float amin = fmaxf(fmaxf(axmin, aymin), fmaxf(azmin, 0.0f));
  float amax = fminf(fminf(axmax, aymax), fminf(azmax, 1.0f));

  float acc0 = 0.0f, acc1 = 0.0f;
  if (amax > amin) {
    float s      = (amax - amin) * (1.0f / (float)K);
    float astart = fmaf((float)k, s, amin);
    float aend   = (k == K - 1) ? amax : fmaf((float)(k + 1), s, amin);

    TState S;
    S.acur = astart; S.aend = aend;
    int cx, cy, cz;
    axis_init(astart, aend, p0x, dsx, invx, S.stx, S.ix, S.alx, S.dax, cx);
    axis_init(astart, aend, p0y, dsy, invy, S.sty, S.iy, S.aly, S.day, cy);
    axis_init(astart, aend, p0z, dsz, invz, S.stz, S.iz, S.alz, S.daz, cz);

    int ns = cx + cy + cz + 3;          // +1 final partial, +2 cushion
    int nb = (ns + 3) >> 2;             // batches of 4
    if (nb < 2) nb = 2;                 // prologue needs two batches

    int   idxA[4], idxB[4], idxC[4];
    float difA[4], difB[4], difC[4];
    float vA[4], vB[4], vC[4];

#define ISSUE(X)                                                    \
    do { step4(S, idx##X, dif##X);                                  \
         v##X[0] = image[idx##X[0]]; v##X[1] = image[idx##X[1]];    \
         v##X[2] = image[idx##X[2]]; v##X[3] = image[idx##X[3]]; } while (0)
#define CONSUME(X)                                                  \
    do { acc0 = fmaf(dif##X[0], v##X[0], acc0);                     \
         acc1 = fmaf(dif##X[1], v##X[1], acc1);                     \
         acc0 = fmaf(dif##X[2], v##X[2], acc0);                     \
         acc1 = fmaf(dif##X[3], v##X[3], acc1); } while (0)

    ISSUE(A);
    ISSUE(B);
    int produce = nb - 2;               // batches still to produce
    while (produce >= 3) {
      ISSUE(C); CONSUME(A);
      ISSUE(A); CONSUME(B);
      ISSUE(B); CONSUME(C);
      produce -= 3;
    }
    if (produce == 2) {
      ISSUE(C); CONSUME(A);
      ISSUE(A); CONSUME(B);
      CONSUME(C); CONSUME(A);
    } else if (produce == 1) {
      ISSUE(C); CONSUME(A);
      CONSUME(B); CONSUME(C);
    } else {
      CONSUME(A); CONSUME(B);
    }
#undef ISSUE
#undef CONSUME

    float rlen = sqrtf(dx * dx + dy * dy + dz * dz);
    acc0 = (acc0 + acc1) * rlen;
    acc1 = 0.0f;
  }

  // Reduce the K chunk partials within each 16-lane group.
  float acc = acc0 + acc1;
  acc += __shfl_xor(acc, 1);
  acc += __shfl_xor(acc, 2);
  acc += __shfl_xor(acc, 4);
  acc += __shfl_xor(acc, 8);
  if (k == 0) out[ray] = acc;
}

extern "C" void kernel_launch(void* const* d_in, const int* in_sizes, int n_in,
                              void* d_out, int out_size, void* d_ws, size_t ws_size,
                              hipStream_t stream) {
  const float* image = (const float*)d_in[0];   // [128,128,128] f32
  const float* lors  = (const float*)d_in[1];   // [N,6] f32
  float* out = (float*)d_out;                   // [N] f32
  int n = out_size;
  long total = (long)n * K;
  int block = 256;
  int grid = (int)((total + block - 1) / block);
  hipLaunchKernelGGL(siddon_fp, dim3(grid), dim3(block), 0, stream,
                     image, lors, out, n);
}